// Round 10
// baseline (152.408 us; speedup 1.0000x reference)
//
#include <hip/hip_runtime.h>
#include <stdint.h>

typedef __bf16 bf16x8 __attribute__((ext_vector_type(8)));
typedef float f32x4 __attribute__((ext_vector_type(4)));

__device__ __forceinline__ uint16_t f2bf(float f) {
  union { float f; uint32_t u; } c; c.f = f;
  uint32_t u = c.u;
  u += 0x7fffu + ((u >> 16) & 1u);   // round-to-nearest-even
  return (uint16_t)(u >> 16);
}
__device__ __forceinline__ float bf2f(uint16_t u) {
  union { uint32_t u; float f; } c; c.u = (uint32_t)u << 16; return c.f;
}

// ---------------- fused preamble: cvt x, cvt Wv, 3 transposes, bc ----------------
__device__ __forceinline__ void cvt_body(const float* __restrict__ in,
                                         uint16_t* __restrict__ out, int i) {
  float4 v = reinterpret_cast<const float4*>(in)[i];
  ushort4 o;
  o.x = f2bf(v.x); o.y = f2bf(v.y); o.z = f2bf(v.z); o.w = f2bf(v.w);
  reinterpret_cast<ushort4*>(out)[i] = o;
}

__global__ void prep_kernel(const float* __restrict__ x, const float* __restrict__ Wv,
                            const float* __restrict__ Wo, const float* __restrict__ W1,
                            const float* __restrict__ W2, const float* __restrict__ bv,
                            const float* __restrict__ bo,
                            uint16_t* __restrict__ xb, uint16_t* __restrict__ wvb,
                            uint16_t* __restrict__ woT, uint16_t* __restrict__ w1t,
                            uint16_t* __restrict__ w2t, float* __restrict__ bc) {
  __shared__ float tsh[32][33];
  __shared__ float red[8][32];
  int b = blockIdx.x;
  const int t = threadIdx.x;
  if (b < 4096) { cvt_body(x, xb, b * 256 + t); return; }
  b -= 4096;
  if (b < 1024) { cvt_body(Wv, wvb, b * 256 + t); return; }
  b -= 1024;

  const float* tin = nullptr; uint16_t* tout = nullptr;
  int R = 0, C = 0, bx = 0, by = 0;
  if (b < 1024) {                      // Wo^T: 1024x1024
    tin = Wo; tout = woT; R = 1024; C = 1024; bx = b & 31; by = b >> 5;
  } else if (b < 1024 + 4096) {        // W1^T: [1024,4096] -> [4096,1024]
    const int bb = b - 1024;
    tin = W1; tout = w1t; R = 1024; C = 4096; bx = bb & 127; by = bb >> 7;
  } else if (b < 1024 + 8192) {        // W2^T: [4096,1024] -> [1024,4096]
    const int bb = b - (1024 + 4096);
    tin = W2; tout = w2t; R = 4096; C = 1024; bx = bb & 31; by = bb >> 5;
  } else {                             // bc = bv @ Wo + bo : 32 blocks
    const int jb = b - (1024 + 8192);
    const int jl = t & 31, kg = t >> 5;
    const int j = jb * 32 + jl;
    float s = 0.f;
    const int k0 = kg * 128;
    for (int k = k0; k < k0 + 128; ++k) s += bv[k] * Wo[(size_t)k * 1024 + j];
    red[kg][jl] = s;
    __syncthreads();
    if (kg == 0) {
      float acc = bo[j];
#pragma unroll
      for (int q = 0; q < 8; ++q) acc += red[q][jl];
      bc[j] = acc;
    }
    return;
  }
  const int tx = t & 31, ty = t >> 5;
  const int c0 = bx * 32, r0 = by * 32;
#pragma unroll
  for (int i = 0; i < 4; ++i)
    tsh[ty + i * 8][tx] = tin[(size_t)(r0 + ty + i * 8) * C + (c0 + tx)];
  __syncthreads();
#pragma unroll
  for (int i = 0; i < 4; ++i)
    tout[(size_t)(c0 + ty + i * 8) * R + (r0 + tx)] = f2bf(tsh[tx][ty + i * 8]);
}

// ---------------- 2-phase 128x128 GEMM (small GEMMs; 0 bank conflicts measured) ----------------
// Supports split-K via blockIdx.z: A += z*Klen, Bt += z*Klen, out += z*M*N (MODE 0).
// MODE 0: bf16(acc + bias?) at z-offset   MODE 1: bf16(acc + bias + res_f32), z ignored
constexpr int BM = 128, BN = 128, BK = 64;

template <int MODE>
__launch_bounds__(256, 2)
__global__ void gemm2ph_kernel(const uint16_t* __restrict__ A, const uint16_t* __restrict__ Bt,
                               const float* __restrict__ bias, const float* __restrict__ res,
                               void* __restrict__ out, int M, int N, int Klen, int lda, int ldb) {
  __shared__ uint16_t sAB[2][2][BM * BK];
  const int tid  = threadIdx.x;
  const int lane = tid & 63;
  const int wave = tid >> 6;

  const int nwg = gridDim.x * gridDim.y;
  int wg = blockIdx.y * gridDim.x + blockIdx.x;
  wg = (wg & 7) * (nwg >> 3) + (wg >> 3);
  const int bx = wg % gridDim.x, by = wg / gridDim.x;
  const int m0 = by * BM, n0 = bx * BN;

  const int z = blockIdx.z;
  A  += (size_t)z * Klen;
  Bt += (size_t)z * Klen;

  const int wm = (wave >> 1) * 64;
  const int wn = (wave & 1) * 64;

  f32x4 acc[4][4] = {};

  const int srow = tid >> 3;
  const int scol = ((tid & 7) ^ (srow & 7)) * 8;
  const uint16_t* ga[4];
  const uint16_t* gb[4];
  uint32_t loff[4];
#pragma unroll
  for (int g = 0; g < 4; ++g) {
    const int row = srow + 32 * g;
    ga[g] = A + (size_t)(m0 + row) * lda + scol;
    gb[g] = Bt + (size_t)(n0 + row) * ldb + scol;
    loff[g] = (uint32_t)(tid + g * 256) * 8;
  }

  const int fr = lane & 15;
  const int hi = lane >> 4;
  const int rx = fr & 7;

  const int nk = Klen / BK;

#define STAGE2(buf, kt)                                                                   \
  {                                                                                       \
    _Pragma("unroll")                                                                     \
    for (int g = 0; g < 4; ++g) {                                                         \
      __builtin_amdgcn_global_load_lds(                                                   \
          (const __attribute__((address_space(1))) uint32_t*)(ga[g] + (size_t)(kt) * BK), \
          (__attribute__((address_space(3))) uint32_t*)(&sAB[buf][0][loff[g]]), 16, 0, 0);\
      __builtin_amdgcn_global_load_lds(                                                   \
          (const __attribute__((address_space(1))) uint32_t*)(gb[g] + (size_t)(kt) * BK), \
          (__attribute__((address_space(3))) uint32_t*)(&sAB[buf][1][loff[g]]), 16, 0, 0);\
    }                                                                                     \
  }

  STAGE2(0, 0);
  __syncthreads();

  int cur = 0;
  for (int kt = 0; kt < nk; ++kt) {
    if (kt + 1 < nk) STAGE2(cur ^ 1, kt + 1);
    const uint16_t* pA = &sAB[cur][0][0];
    const uint16_t* pB = &sAB[cur][1][0];
    bf16x8 af[4][2], bb[4][2];
#pragma unroll
    for (int m = 0; m < 4; ++m)
#pragma unroll
      for (int ks = 0; ks < 2; ++ks) {
        const int slot = (ks * 4 + hi) ^ rx;
        af[m][ks] = *reinterpret_cast<const bf16x8*>(pA + (wm + m * 16 + fr) * BK + slot * 8);
        bb[m][ks] = *reinterpret_cast<const bf16x8*>(pB + (wn + m * 16 + fr) * BK + slot * 8);
      }
#pragma unroll
    for (int ks = 0; ks < 2; ++ks)
#pragma unroll
      for (int m = 0; m < 4; ++m)
#pragma unroll
        for (int n = 0; n < 4; ++n)
          acc[m][n] = __builtin_amdgcn_mfma_f32_16x16x32_bf16(af[m][ks], bb[n][ks], acc[m][n], 0, 0, 0);
    __syncthreads();
    cur ^= 1;
  }
#undef STAGE2

  const int cn  = lane & 15;
  const int cm4 = (lane >> 4) * 4;
  uint16_t* outp = (uint16_t*)out + (size_t)z * M * N;   // MODE 0 split-K offset
#pragma unroll
  for (int m = 0; m < 4; ++m) {
#pragma unroll
    for (int n = 0; n < 4; ++n) {
      const int gm = m0 + wm + m * 16 + cm4;
      const int gn = n0 + wn + n * 16 + cn;
      const float bbv = bias ? bias[gn] : 0.f;
#pragma unroll
      for (int r = 0; r < 4; ++r) {
        const size_t idx = (size_t)(gm + r) * N + gn;
        const float vv = acc[m][n][r] + bbv;
        if constexpr (MODE == 0) {
          outp[idx] = f2bf(vv);
        } else {
          ((uint16_t*)out)[idx] = f2bf(vv + res[idx]);
        }
      }
    }
  }
}

// ---------------- combine 4 bf16 partials -> bf16 ----------------
__global__ void comb4_kernel(const uint16_t* __restrict__ wp, size_t stride,
                             uint16_t* __restrict__ o, int n4) {
  const int i = blockIdx.x * 256 + threadIdx.x;
  if (i >= n4) return;
  float4 v = {0.f, 0.f, 0.f, 0.f};
#pragma unroll
  for (int zz = 0; zz < 4; ++zz) {
    const ushort4 p = reinterpret_cast<const ushort4*>(wp + zz * stride)[i];
    v.x += bf2f(p.x); v.y += bf2f(p.y); v.z += bf2f(p.z); v.w += bf2f(p.w);
  }
  ushort4 r;
  r.x = f2bf(v.x); r.y = f2bf(v.y); r.z = f2bf(v.z); r.w = f2bf(v.w);
  reinterpret_cast<ushort4*>(o)[i] = r;
}

// ---------------- 256x256 GEMM v6: 1 barrier / K-tile via triple-buffered B ----------------
// LDS 160KB: A 2 bufs x 16384 elems @0; B 3 bufs x 16384 elems @32768. key = row&7 swizzle.
// Per K-tile: 24 ds_reads (all up front; compiler fine-lgkm under MFMA), stage A(k+1)->
// opposite A-buf, stage B(k+2)->buf (k+2)%3 (disjoint from k%3,(k+1)%3 -> NO WAR hazard,
// race-free by region disjointness), 64 MFMA, vmcnt(4) [tail 0], lgkm pin, ONE barrier.
// FIFO ledger: prologue {A0,B0,B1}+vmcnt(4); steady end-of-k outstanding
// [B(k+1),A(k+1),B(k+2)]=12 -> vmcnt(4) drains tile k+1 exactly; k>=nk-2 -> vmcnt(0).
// MODE 0: bf16(relu(acc+bias))   MODE 1: bf16(acc) -> out + z*M*N (split-K partial)
template <int MODE>
__launch_bounds__(512, 2)
__global__ void gemm8ph_kernel(const uint16_t* __restrict__ A, const uint16_t* __restrict__ Bt,
                               const float* __restrict__ bias, void* __restrict__ out,
                               int M, int N, int Klen, int lda, int ldb) {
  extern __shared__ uint16_t lds[];   // 81920 elems = 160 KB
  const int tid  = threadIdx.x;
  const int lane = tid & 63;
  const int wave = tid >> 6;

  const int nwg = gridDim.x * gridDim.y;
  int wg = blockIdx.y * gridDim.x + blockIdx.x;
  wg = (wg & 7) * (nwg >> 3) + (wg >> 3);
  const int bx = wg % gridDim.x, by = wg / gridDim.x;
  const int m0 = by * 256, n0 = bx * 256;

  const int z = blockIdx.z;
  A  += (size_t)z * Klen;
  Bt += (size_t)z * Klen;

  const int wm = (wave >> 2) * 128;
  const int wn = (wave & 3) * 64;

  f32x4 acc[8][4] = {};

  const int srw = tid >> 3;            // 0..63
  const int sp  = tid & 7;
  const uint16_t* gu[8];
#pragma unroll
  for (int u = 0; u < 8; ++u) {
    const uint16_t* base = (u < 4) ? A + (size_t)(m0 + u * 64) * lda
                                   : Bt + (size_t)(n0 + (u - 4) * 64) * ldb;
    const int ld = (u < 4) ? lda : ldb;
    gu[u] = base + (size_t)srw * ld + ((sp ^ (srw & 7)) * 8);   // key: row&7
  }

  const int nk = Klen / 64;

#define STAGE_A(T)                                                                            \
  if ((T) < nk) {                                                                             \
    _Pragma("unroll")                                                                         \
    for (int u = 0; u < 4; ++u)                                                               \
      __builtin_amdgcn_global_load_lds(                                                       \
          (const __attribute__((address_space(1))) uint32_t*)(gu[u] + (size_t)(T) * 64),      \
          (__attribute__((address_space(3))) uint32_t*)(lds + ((T) & 1) * 16384 + u * 4096 +  \
                                                        tid * 8),                             \
          16, 0, 0);                                                                          \
  }
#define STAGE_B(T, BUF)                                                                       \
  if ((T) < nk) {                                                                             \
    _Pragma("unroll")                                                                         \
    for (int u = 4; u < 8; ++u)                                                               \
      __builtin_amdgcn_global_load_lds(                                                       \
          (const __attribute__((address_space(1))) uint32_t*)(gu[u] + (size_t)(T) * 64),      \
          (__attribute__((address_space(3))) uint32_t*)(lds + 32768 + (BUF) * 16384 +         \
                                                        (u - 4) * 4096 + tid * 8),            \
          16, 0, 0);                                                                          \
  }

  const int fr = lane & 15;
  const int hi = lane >> 4;
  int aoff[8];                         // relative to A-buf base
#pragma unroll
  for (int m = 0; m < 8; ++m) {
    const int u = (wm >> 6) + (m >> 2);
    const int R = (m & 3) * 16 + fr;
    aoff[m] = u * 4096 + R * 64 + ((hi ^ (R & 7)) * 8);
  }
  int boff[4];                         // relative to B-buf base
#pragma unroll
  for (int n = 0; n < 4; ++n) {
    const int u = wn >> 6;
    const int R = n * 16 + fr;
    boff[n] = u * 4096 + R * 64 + ((hi ^ (R & 7)) * 8);
  }

  // ---- prologue: A(0)->buf0, B(0)->buf0, B(1)->buf1; vmcnt(4) leaves B(1) in flight ----
  STAGE_A(0);
  STAGE_B(0, 0);
  STAGE_B(1, 1);
  asm volatile("s_waitcnt vmcnt(4)" ::: "memory");
  __builtin_amdgcn_s_barrier();

#define LD8(p, off) (*reinterpret_cast<const bf16x8*>((p) + (off)))
#define MFMA32(AQ, KS)                                                        \
  __builtin_amdgcn_s_setprio(1);                                              \
  _Pragma("unroll") for (int mm = 0; mm < 8; ++mm)                            \
    _Pragma("unroll") for (int n = 0; n < 4; ++n)                             \
      acc[mm][n] = __builtin_amdgcn_mfma_f32_16x16x32_bf16(                   \
          AQ[mm], bq[n][KS], acc[mm][n], 0, 0, 0);                            \
  __builtin_amdgcn_s_setprio(0);

  int bcur = 0, b2 = 2;
  for (int k = 0; k < nk; ++k) {
    const uint16_t* bufA = lds + (k & 1) * 16384;
    const uint16_t* bufB = lds + 32768 + bcur * 16384;
    bf16x8 bq[4][2], aq0[8], aq1[8];
#pragma unroll
    for (int n = 0; n < 4; ++n) { bq[n][0] = LD8(bufB, boff[n]); bq[n][1] = LD8(bufB, boff[n] ^ 32); }
#pragma unroll
    for (int mm = 0; mm < 8; ++mm) { aq0[mm] = LD8(bufA, aoff[mm]); aq1[mm] = LD8(bufA, aoff[mm] ^ 32); }
    STAGE_A(k + 1);                    // opposite A-buf: never a hazard
    STAGE_B(k + 2, b2);                // third B-buf: disjoint from bcur and next
    MFMA32(aq0, 0);
    MFMA32(aq1, 1);
    if (k < nk - 2) { asm volatile("s_waitcnt vmcnt(4)" ::: "memory"); }
    else            { asm volatile("s_waitcnt vmcnt(0)" ::: "memory"); }
    asm volatile("s_waitcnt lgkmcnt(0)" ::: "memory");   // free (reads consumed); pins order
    __builtin_amdgcn_s_barrier();
    bcur = (bcur == 2) ? 0 : bcur + 1;
    b2   = (b2 == 2)   ? 0 : b2 + 1;
  }
#undef MFMA32
#undef LD8
#undef STAGE_A
#undef STAGE_B

  const int cn  = lane & 15;
  const int cm4 = (lane >> 4) * 4;
  uint16_t* outp = (uint16_t*)out;
  if constexpr (MODE == 1) outp += (size_t)z * M * N;
  float bias_n[4];
  if constexpr (MODE == 0) {
#pragma unroll
    for (int n = 0; n < 4; ++n) bias_n[n] = bias[n0 + wn + n * 16 + cn];
  }
#pragma unroll
  for (int m = 0; m < 8; ++m) {
#pragma unroll
    for (int n = 0; n < 4; ++n) {
      const int gm = m0 + wm + m * 16 + cm4;
      const int gn = n0 + wn + n * 16 + cn;
#pragma unroll
      for (int r = 0; r < 4; ++r) {
        const size_t idx = (size_t)(gm + r) * N + gn;
        if constexpr (MODE == 0) {
          outp[idx] = f2bf(fmaxf(acc[m][n][r] + bias_n[n], 0.f));
        } else {
          outp[idx] = f2bf(acc[m][n][r]);
        }
      }
    }
  }
}

// ---------------- LN1: hb = bf16(LN(q0+q1+xb+bc)*g + b) ----------------
__global__ void ln1_kernel(const uint16_t* __restrict__ q0, const uint16_t* __restrict__ q1,
                           const uint16_t* __restrict__ xb, const float* __restrict__ bc,
                           const float* __restrict__ g, const float* __restrict__ b,
                           uint16_t* __restrict__ outb) {
  const int row = blockIdx.x;
  const int t = threadIdx.x;
  const size_t base = (size_t)row * 1024;
  const ushort4 a4 = reinterpret_cast<const ushort4*>(q0 + base)[t];
  const ushort4 b4 = reinterpret_cast<const ushort4*>(q1 + base)[t];
  const ushort4 x4 = reinterpret_cast<const ushort4*>(xb + base)[t];
  const float4 c4 = reinterpret_cast<const float4*>(bc)[t];
  float4 v;
  v.x = bf2f(a4.x) + bf2f(b4.x) + bf2f(x4.x) + c4.x;
  v.y = bf2f(a4.y) + bf2f(b4.y) + bf2f(x4.y) + c4.y;
  v.z = bf2f(a4.z) + bf2f(b4.z) + bf2f(x4.z) + c4.z;
  v.w = bf2f(a4.w) + bf2f(b4.w) + bf2f(x4.w) + c4.w;
  float s  = v.x + v.y + v.z + v.w;
  float s2 = v.x * v.x + v.y * v.y + v.z * v.z + v.w * v.w;
#pragma unroll
  for (int o = 32; o > 0; o >>= 1) { s += __shfl_down(s, o); s2 += __shfl_down(s2, o); }
  __shared__ float red[8];
  const int lane = t & 63, wave = t >> 6;
  if (lane == 0) { red[wave] = s; red[4 + wave] = s2; }
  __syncthreads();
  const float S  = red[0] + red[1] + red[2] + red[3];
  const float S2 = red[4] + red[5] + red[6] + red[7];
  const float mu  = S * (1.f / 1024.f);
  const float var = S2 * (1.f / 1024.f) - mu * mu;
  const float rs  = rsqrtf(var + 1e-5f);
  const float4 gg = reinterpret_cast<const float4*>(g)[t];
  const float4 bb = reinterpret_cast<const float4*>(b)[t];
  ushort4 ob;
  ob.x = f2bf((v.x - mu) * rs * gg.x + bb.x);
  ob.y = f2bf((v.y - mu) * rs * gg.y + bb.y);
  ob.z = f2bf((v.z - mu) * rs * gg.z + bb.z);
  ob.w = f2bf((v.w - mu) * rs * gg.w + bb.w);
  reinterpret_cast<ushort4*>(outb + base)[t] = ob;
}

// ---------------- LN2: out = LN(sum_z pp[z] + b2 + h)*g + be ----------------
__global__ void ln2_kernel(const uint16_t* __restrict__ pp, size_t pstride,
                           const uint16_t* __restrict__ hb, const float* __restrict__ b2,
                           const float* __restrict__ g, const float* __restrict__ be,
                           float* __restrict__ out) {
  const int row = blockIdx.x;
  const int t = threadIdx.x;
  const size_t base = (size_t)row * 1024;
  const ushort4 h4 = reinterpret_cast<const ushort4*>(hb + base)[t];
  const float4 c2 = reinterpret_cast<const float4*>(b2)[t];
  float4 v;
  v.x = c2.x + bf2f(h4.x); v.y = c2.y + bf2f(h4.y);
  v.z = c2.z + bf2f(h4.z); v.w = c2.w + bf2f(h4.w);
#pragma unroll
  for (int zz = 0; zz < 4; ++zz) {
    const ushort4 p4 = reinterpret_cast<const ushort4*>(pp + zz * pstride + base)[t];
    v.x += bf2f(p4.x); v.y += bf2f(p4.y); v.z += bf2f(p4.z); v.w += bf2f(p4.w);
  }
  float s  = v.x + v.y + v.z + v.w;
  float s2 = v.x * v.x + v.y * v.y + v.z * v.z + v.w * v.w;
#pragma unroll
  for (int o = 32; o > 0; o >>= 1) { s += __shfl_down(s, o); s2 += __shfl_down(s2, o); }
  __shared__ float red[8];
  const int lane = t & 63, wave = t >> 6;
  if (lane == 0) { red[wave] = s; red[4 + wave] = s2; }
  __syncthreads();
  const float S  = red[0] + red[1] + red[2] + red[3];
  const float S2 = red[4] + red[5] + red[6] + red[7];
  const float mu  = S * (1.f / 1024.f);
  const float var = S2 * (1.f / 1024.f) - mu * mu;
  const float rs  = rsqrtf(var + 1e-5f);
  const float4 gg = reinterpret_cast<const float4*>(g)[t];
  const float4 bb = reinterpret_cast<const float4*>(be)[t];
  float4 o;
  o.x = (v.x - mu) * rs * gg.x + bb.x;
  o.y = (v.y - mu) * rs * gg.y + bb.y;
  o.z = (v.z - mu) * rs * gg.z + bb.z;
  o.w = (v.w - mu) * rs * gg.w + bb.w;
  reinterpret_cast<float4*>(out + base)[t] = o;
}

// ---------------- launch ----------------
extern "C" void kernel_launch(void* const* d_in, const int* in_sizes, int n_in,
                              void* d_out, int out_size, void* d_ws, size_t ws_size,
                              hipStream_t stream) {
  // hollow attention == identity: out = attn@v = v, so the layer is
  // r1 = x + x@(Wv@Wo) + (bv@Wo+bo); h = LN1(r1); r2 = h + relu(h@W1+b1)@W2 + b2; out = LN2(r2)
  const float* x   = (const float*)d_in[0];
  const float* Wv  = (const float*)d_in[6];
  const float* bv  = (const float*)d_in[7];
  const float* Wo  = (const float*)d_in[8];
  const float* bo  = (const float*)d_in[9];
  const float* W1  = (const float*)d_in[10];
  const float* b1  = (const float*)d_in[11];
  const float* W2  = (const float*)d_in[12];
  const float* b2  = (const float*)d_in[13];
  const float* g1  = (const float*)d_in[14];
  const float* be1 = (const float*)d_in[15];
  const float* g2  = (const float*)d_in[16];
  const float* be2 = (const float*)d_in[17];
  float* out = (float*)d_out;

  constexpr int M = 4096, DM = 1024, FF = 4096;

  char* p = (char*)d_ws;
  auto alloc = [&](size_t bytes) {
    char* r = p;
    p += (bytes + 255) & ~(size_t)255;
    return r;
  };
  uint16_t* xb  = (uint16_t*)alloc((size_t)M * DM * 2);
  uint16_t* wvb = (uint16_t*)alloc((size_t)DM * DM * 2);
  uint16_t* woT = (uint16_t*)alloc((size_t)DM * DM * 2);
  uint16_t* w1t = (uint16_t*)alloc((size_t)FF * DM * 2);
  uint16_t* w2t = (uint16_t*)alloc((size_t)DM * FF * 2);
  uint16_t* wcT = (uint16_t*)alloc((size_t)DM * DM * 2);
  float*    bc  = (float*)   alloc((size_t)DM * 4);
  uint16_t* hb  = (uint16_t*)alloc((size_t)M * DM * 2);
  uint16_t* tb  = (uint16_t*)alloc((size_t)M * FF * 2);
  uint16_t* pp  = (uint16_t*)alloc((size_t)4 * M * DM * 2);  // split-K bf16 partials (G4)
  // aliases (lifetime-disjoint, serial stream):
  uint16_t* wp = pp;   // wcT partials 4 x 1M bf16 (8MB)  -- pp written later by G4
  uint16_t* q  = tb;   // r1 partials 2 x 4M bf16 (16MB)  -- tb written later by G3

  (void)hipFuncSetAttribute(reinterpret_cast<const void*>(gemm8ph_kernel<0>),
                            hipFuncAttributeMaxDynamicSharedMemorySize, 163840);
  (void)hipFuncSetAttribute(reinterpret_cast<const void*>(gemm8ph_kernel<1>),
                            hipFuncAttributeMaxDynamicSharedMemorySize, 163840);

  // fused preamble: cvt x, cvt Wv, Wo^T, W1^T, W2^T, bc  (one launch)
  prep_kernel<<<4096 + 1024 + 1024 + 4096 + 4096 + 32, 256, 0, stream>>>(
      x, Wv, Wo, W1, W2, bv, bo, xb, wvb, woT, w1t, w2t, bc);

  // wp[z] = partial (Wv@Wo)^T  [split-K=4, nk=4 each]
  gemm2ph_kernel<0><<<dim3(DM / BN, DM / BM, 4), 256, 0, stream>>>(
      woT, wvb, nullptr, nullptr, wp, DM, DM, DM / 4, DM, DM);
  // wcT = sum_z wp[z]
  comb4_kernel<<<DM * DM / 4 / 256, 256, 0, stream>>>(wp, (size_t)DM * DM, wcT, DM * DM / 4);
  // q[z] = partial x@Wc  [split-K=2, nk=8 each]
  gemm2ph_kernel<0><<<dim3(DM / BN, M / BM, 2), 256, 0, stream>>>(
      xb, wcT, nullptr, nullptr, q, M, DM, DM / 2, DM, DM);
  // h = LN1(q0 + q1 + x + bc)
  ln1_kernel<<<M, 256, 0, stream>>>(q, q + (size_t)M * DM, xb, bc, g1, be1, hb);
  // t = relu(h@W1 + b1)   [v6: 1 barrier/K-tile, triple-buffered B]
  gemm8ph_kernel<0><<<dim3(FF / 256, M / 256), 512, 163840, stream>>>(
      hb, w1t, b1, tb, M, FF, DM, DM, DM);
  // pp[z] = t[:, z*1024:(z+1)*1024] @ W2[z*1024:(z+1)*1024, :]   [v6, split-K=4]
  gemm8ph_kernel<1><<<dim3(DM / 256, M / 256, 4), 512, 163840, stream>>>(
      tb, w2t, nullptr, pp, M, DM, FF / 4, FF, FF);
  // out = LN2(h + sum_z pp[z] + b2)
  ln2_kernel<<<M, 256, 0, stream>>>(pp, (size_t)M * DM, hb, b2, g2, be2, out);
}

// Round 11
// 138.352 us; speedup vs baseline: 1.1016x; 1.1016x over previous
//
#include <hip/hip_runtime.h>
#include <stdint.h>

typedef __bf16 bf16x8 __attribute__((ext_vector_type(8)));
typedef float f32x4 __attribute__((ext_vector_type(4)));

__device__ __forceinline__ uint16_t f2bf(float f) {
  union { float f; uint32_t u; } c; c.f = f;
  uint32_t u = c.u;
  u += 0x7fffu + ((u >> 16) & 1u);   // round-to-nearest-even
  return (uint16_t)(u >> 16);
}
__device__ __forceinline__ float bf2f(uint16_t u) {
  union { uint32_t u; float f; } c; c.u = (uint32_t)u << 16; return c.f;
}

// ---------------- fused preamble: cvt x, cvt Wv, 3 transposes, bc ----------------
__device__ __forceinline__ void cvt_body(const float* __restrict__ in,
                                         uint16_t* __restrict__ out, int i) {
  float4 v = reinterpret_cast<const float4*>(in)[i];
  ushort4 o;
  o.x = f2bf(v.x); o.y = f2bf(v.y); o.z = f2bf(v.z); o.w = f2bf(v.w);
  reinterpret_cast<ushort4*>(out)[i] = o;
}

__global__ void prep_kernel(const float* __restrict__ x, const float* __restrict__ Wv,
                            const float* __restrict__ Wo, const float* __restrict__ W1,
                            const float* __restrict__ W2, const float* __restrict__ bv,
                            const float* __restrict__ bo,
                            uint16_t* __restrict__ xb, uint16_t* __restrict__ wvb,
                            uint16_t* __restrict__ woT, uint16_t* __restrict__ w1t,
                            uint16_t* __restrict__ w2t, float* __restrict__ bc) {
  __shared__ float tsh[32][33];
  __shared__ float red[8][32];
  int b = blockIdx.x;
  const int t = threadIdx.x;
  if (b < 4096) { cvt_body(x, xb, b * 256 + t); return; }
  b -= 4096;
  if (b < 1024) { cvt_body(Wv, wvb, b * 256 + t); return; }
  b -= 1024;

  const float* tin = nullptr; uint16_t* tout = nullptr;
  int R = 0, C = 0, bx = 0, by = 0;
  if (b < 1024) {                      // Wo^T: 1024x1024
    tin = Wo; tout = woT; R = 1024; C = 1024; bx = b & 31; by = b >> 5;
  } else if (b < 1024 + 4096) {        // W1^T: [1024,4096] -> [4096,1024]
    const int bb = b - 1024;
    tin = W1; tout = w1t; R = 1024; C = 4096; bx = bb & 127; by = bb >> 7;
  } else if (b < 1024 + 8192) {        // W2^T: [4096,1024] -> [1024,4096]
    const int bb = b - (1024 + 4096);
    tin = W2; tout = w2t; R = 4096; C = 1024; bx = bb & 31; by = bb >> 5;
  } else {                             // bc = bv @ Wo + bo : 32 blocks
    const int jb = b - (1024 + 8192);
    const int jl = t & 31, kg = t >> 5;
    const int j = jb * 32 + jl;
    float s = 0.f;
    const int k0 = kg * 128;
    for (int k = k0; k < k0 + 128; ++k) s += bv[k] * Wo[(size_t)k * 1024 + j];
    red[kg][jl] = s;
    __syncthreads();
    if (kg == 0) {
      float acc = bo[j];
#pragma unroll
      for (int q = 0; q < 8; ++q) acc += red[q][jl];
      bc[j] = acc;
    }
    return;
  }
  const int tx = t & 31, ty = t >> 5;
  const int c0 = bx * 32, r0 = by * 32;
#pragma unroll
  for (int i = 0; i < 4; ++i)
    tsh[ty + i * 8][tx] = tin[(size_t)(r0 + ty + i * 8) * C + (c0 + tx)];
  __syncthreads();
#pragma unroll
  for (int i = 0; i < 4; ++i)
    tout[(size_t)(c0 + ty + i * 8) * R + (r0 + tx)] = f2bf(tsh[tx][ty + i * 8]);
}

// ---------------- 2-phase 128x128 GEMM (small GEMMs; 0 bank conflicts measured) ----------------
// Supports split-K via blockIdx.z: A += z*Klen, Bt += z*Klen, out += z*M*N (MODE 0).
// MODE 0: bf16(acc + bias?) at z-offset   MODE 1: bf16(acc + bias + res_f32), z ignored
constexpr int BM = 128, BN = 128, BK = 64;

template <int MODE>
__launch_bounds__(256, 2)
__global__ void gemm2ph_kernel(const uint16_t* __restrict__ A, const uint16_t* __restrict__ Bt,
                               const float* __restrict__ bias, const float* __restrict__ res,
                               void* __restrict__ out, int M, int N, int Klen, int lda, int ldb) {
  __shared__ uint16_t sAB[2][2][BM * BK];
  const int tid  = threadIdx.x;
  const int lane = tid & 63;
  const int wave = tid >> 6;

  const int nwg = gridDim.x * gridDim.y;
  int wg = blockIdx.y * gridDim.x + blockIdx.x;
  wg = (wg & 7) * (nwg >> 3) + (wg >> 3);
  const int bx = wg % gridDim.x, by = wg / gridDim.x;
  const int m0 = by * BM, n0 = bx * BN;

  const int z = blockIdx.z;
  A  += (size_t)z * Klen;
  Bt += (size_t)z * Klen;

  const int wm = (wave >> 1) * 64;
  const int wn = (wave & 1) * 64;

  f32x4 acc[4][4] = {};

  const int srow = tid >> 3;
  const int scol = ((tid & 7) ^ (srow & 7)) * 8;
  const uint16_t* ga[4];
  const uint16_t* gb[4];
  uint32_t loff[4];
#pragma unroll
  for (int g = 0; g < 4; ++g) {
    const int row = srow + 32 * g;
    ga[g] = A + (size_t)(m0 + row) * lda + scol;
    gb[g] = Bt + (size_t)(n0 + row) * ldb + scol;
    loff[g] = (uint32_t)(tid + g * 256) * 8;
  }

  const int fr = lane & 15;
  const int hi = lane >> 4;
  const int rx = fr & 7;

  const int nk = Klen / BK;

#define STAGE2(buf, kt)                                                                   \
  {                                                                                       \
    _Pragma("unroll")                                                                     \
    for (int g = 0; g < 4; ++g) {                                                         \
      __builtin_amdgcn_global_load_lds(                                                   \
          (const __attribute__((address_space(1))) uint32_t*)(ga[g] + (size_t)(kt) * BK), \
          (__attribute__((address_space(3))) uint32_t*)(&sAB[buf][0][loff[g]]), 16, 0, 0);\
      __builtin_amdgcn_global_load_lds(                                                   \
          (const __attribute__((address_space(1))) uint32_t*)(gb[g] + (size_t)(kt) * BK), \
          (__attribute__((address_space(3))) uint32_t*)(&sAB[buf][1][loff[g]]), 16, 0, 0);\
    }                                                                                     \
  }

  STAGE2(0, 0);
  __syncthreads();

  int cur = 0;
  for (int kt = 0; kt < nk; ++kt) {
    if (kt + 1 < nk) STAGE2(cur ^ 1, kt + 1);
    const uint16_t* pA = &sAB[cur][0][0];
    const uint16_t* pB = &sAB[cur][1][0];
    bf16x8 af[4][2], bb[4][2];
#pragma unroll
    for (int m = 0; m < 4; ++m)
#pragma unroll
      for (int ks = 0; ks < 2; ++ks) {
        const int slot = (ks * 4 + hi) ^ rx;
        af[m][ks] = *reinterpret_cast<const bf16x8*>(pA + (wm + m * 16 + fr) * BK + slot * 8);
        bb[m][ks] = *reinterpret_cast<const bf16x8*>(pB + (wn + m * 16 + fr) * BK + slot * 8);
      }
#pragma unroll
    for (int ks = 0; ks < 2; ++ks)
#pragma unroll
      for (int m = 0; m < 4; ++m)
#pragma unroll
        for (int n = 0; n < 4; ++n)
          acc[m][n] = __builtin_amdgcn_mfma_f32_16x16x32_bf16(af[m][ks], bb[n][ks], acc[m][n], 0, 0, 0);
    __syncthreads();
    cur ^= 1;
  }
#undef STAGE2

  const int cn  = lane & 15;
  const int cm4 = (lane >> 4) * 4;
  uint16_t* outp = (uint16_t*)out + (size_t)z * M * N;   // MODE 0 split-K offset
#pragma unroll
  for (int m = 0; m < 4; ++m) {
#pragma unroll
    for (int n = 0; n < 4; ++n) {
      const int gm = m0 + wm + m * 16 + cm4;
      const int gn = n0 + wn + n * 16 + cn;
      const float bbv = bias ? bias[gn] : 0.f;
#pragma unroll
      for (int r = 0; r < 4; ++r) {
        const size_t idx = (size_t)(gm + r) * N + gn;
        const float vv = acc[m][n][r] + bbv;
        if constexpr (MODE == 0) {
          outp[idx] = f2bf(vv);
        } else {
          ((uint16_t*)out)[idx] = f2bf(vv + res[idx]);
        }
      }
    }
  }
}

// ---------------- combine 4 bf16 partials -> bf16 ----------------
__global__ void comb4_kernel(const uint16_t* __restrict__ wp, size_t stride,
                             uint16_t* __restrict__ o, int n4) {
  const int i = blockIdx.x * 256 + threadIdx.x;
  if (i >= n4) return;
  float4 v = {0.f, 0.f, 0.f, 0.f};
#pragma unroll
  for (int zz = 0; zz < 4; ++zz) {
    const ushort4 p = reinterpret_cast<const ushort4*>(wp + zz * stride)[i];
    v.x += bf2f(p.x); v.y += bf2f(p.y); v.z += bf2f(p.z); v.w += bf2f(p.w);
  }
  ushort4 r;
  r.x = f2bf(v.x); r.y = f2bf(v.y); r.z = f2bf(v.z); r.w = f2bf(v.w);
  reinterpret_cast<ushort4*>(o)[i] = r;
}

// ---------------- 256x256 GEMM v5 (r7/r9 best): 2 barriers/K-tile ----------------
// LDS: 2 bufs x 8 units x [64 rows][64 k] bf16; key = row&7 (measured 0-conflict).
// P0: reads bq(both ks)+aq ks0 (16 ds_reads), stage (k+1).A -> opposite buf,
//     MFMA32 ks0 (compiler fine-lgkm), free lgkmcnt(0) pin, barrier.
// P1: reads aq ks1 (8), stage (k+2).B, MFMA32 ks1, vmcnt(4) [tail 0], pin, barrier.
// FIFO ledger: steady outstanding at k.P1 = [B(k+1),A(k+1),B(k+2)]=12 -> vmcnt(4)
// drains tile k+1 exactly. r10's triple-buffer/1-barrier variant REGRESSED
// (FETCH +2.3MB, fragment VGPR pressure) -- keep this schedule.
// MODE 0: bf16(relu(acc+bias))   MODE 1: bf16(acc) -> out + z*M*N (split-K partial)
template <int MODE>
__launch_bounds__(512, 2)
__global__ void gemm8ph_kernel(const uint16_t* __restrict__ A, const uint16_t* __restrict__ Bt,
                               const float* __restrict__ bias, void* __restrict__ out,
                               int M, int N, int Klen, int lda, int ldb) {
  extern __shared__ uint16_t lds[];   // 2 x 32768 elems = 128 KB
  const int tid  = threadIdx.x;
  const int lane = tid & 63;
  const int wave = tid >> 6;

  const int nwg = gridDim.x * gridDim.y;
  int wg = blockIdx.y * gridDim.x + blockIdx.x;
  wg = (wg & 7) * (nwg >> 3) + (wg >> 3);
  const int bx = wg % gridDim.x, by = wg / gridDim.x;
  const int m0 = by * 256, n0 = bx * 256;

  const int z = blockIdx.z;
  A  += (size_t)z * Klen;
  Bt += (size_t)z * Klen;

  const int wm = (wave >> 2) * 128;
  const int wn = (wave & 3) * 64;

  f32x4 acc[8][4] = {};

  const int srw = tid >> 3;            // 0..63
  const int sp  = tid & 7;
  const uint16_t* gu[8];
#pragma unroll
  for (int u = 0; u < 8; ++u) {
    const uint16_t* base = (u < 4) ? A + (size_t)(m0 + u * 64) * lda
                                   : Bt + (size_t)(n0 + (u - 4) * 64) * ldb;
    const int ld = (u < 4) ? lda : ldb;
    gu[u] = base + (size_t)srw * ld + ((sp ^ (srw & 7)) * 8);   // key: row&7
  }

  const int nk = Klen / 64;

#define STAGE8(T, U)                                                                          \
  if ((T) < nk) {                                                                             \
    __builtin_amdgcn_global_load_lds(                                                         \
        (const __attribute__((address_space(1))) uint32_t*)(gu[U] + (size_t)(T) * 64),        \
        (__attribute__((address_space(3))) uint32_t*)(lds + ((T) & 1) * 32768 + (U) * 4096 +  \
                                                      tid * 8),                               \
        16, 0, 0);                                                                            \
  }

  const int fr = lane & 15;
  const int hi = lane >> 4;
  int aoff[8];
#pragma unroll
  for (int m = 0; m < 8; ++m) {
    const int u = (wm >> 6) + (m >> 2);
    const int R = (m & 3) * 16 + fr;
    aoff[m] = u * 4096 + R * 64 + ((hi ^ (R & 7)) * 8);
  }
  int boff[4];
#pragma unroll
  for (int n = 0; n < 4; ++n) {
    const int u = 4 + (wn >> 6);
    const int R = n * 16 + fr;
    boff[n] = u * 4096 + R * 64 + ((hi ^ (R & 7)) * 8);
  }

  STAGE8(0, 0); STAGE8(0, 1); STAGE8(0, 2); STAGE8(0, 3);
  STAGE8(0, 4); STAGE8(0, 5); STAGE8(0, 6); STAGE8(0, 7);
  STAGE8(1, 4); STAGE8(1, 5); STAGE8(1, 6); STAGE8(1, 7);
  asm volatile("s_waitcnt vmcnt(4)" ::: "memory");
  __builtin_amdgcn_s_barrier();

#define LD8(off) (*reinterpret_cast<const bf16x8*>(bufp + (off)))
#define PHASE_MFMA32(KS)                                                      \
  __builtin_amdgcn_s_setprio(1);                                              \
  _Pragma("unroll") for (int mm = 0; mm < 8; ++mm)                            \
    _Pragma("unroll") for (int n = 0; n < 4; ++n)                             \
      acc[mm][n] = __builtin_amdgcn_mfma_f32_16x16x32_bf16(                   \
          aq[mm], bq[n][KS], acc[mm][n], 0, 0, 0);                            \
  __builtin_amdgcn_s_setprio(0);

  for (int k = 0; k < nk; ++k) {
    const uint16_t* bufp = lds + (k & 1) * 32768;
    bf16x8 bq[4][2], aq[8];
    // ---- P0 ----
#pragma unroll
    for (int n = 0; n < 4; ++n) { bq[n][0] = LD8(boff[n]); bq[n][1] = LD8(boff[n] ^ 32); }
#pragma unroll
    for (int mm = 0; mm < 8; ++mm) aq[mm] = LD8(aoff[mm]);
    STAGE8(k + 1, 0); STAGE8(k + 1, 1); STAGE8(k + 1, 2); STAGE8(k + 1, 3);
    PHASE_MFMA32(0);
    asm volatile("s_waitcnt lgkmcnt(0)" ::: "memory");
    __builtin_amdgcn_s_barrier();
    // ---- P1 ----
#pragma unroll
    for (int mm = 0; mm < 8; ++mm) aq[mm] = LD8(aoff[mm] ^ 32);
    STAGE8(k + 2, 4); STAGE8(k + 2, 5); STAGE8(k + 2, 6); STAGE8(k + 2, 7);
    PHASE_MFMA32(1);
    if (k < nk - 2) { asm volatile("s_waitcnt vmcnt(4)" ::: "memory"); }
    else            { asm volatile("s_waitcnt vmcnt(0)" ::: "memory"); }
    asm volatile("s_waitcnt lgkmcnt(0)" ::: "memory");
    __builtin_amdgcn_s_barrier();
  }
#undef PHASE_MFMA32
#undef LD8
#undef STAGE8

  const int cn  = lane & 15;
  const int cm4 = (lane >> 4) * 4;
  uint16_t* outp = (uint16_t*)out;
  if constexpr (MODE == 1) outp += (size_t)z * M * N;
  float bias_n[4];
  if constexpr (MODE == 0) {
#pragma unroll
    for (int n = 0; n < 4; ++n) bias_n[n] = bias[n0 + wn + n * 16 + cn];
  }
#pragma unroll
  for (int m = 0; m < 8; ++m) {
#pragma unroll
    for (int n = 0; n < 4; ++n) {
      const int gm = m0 + wm + m * 16 + cm4;
      const int gn = n0 + wn + n * 16 + cn;
#pragma unroll
      for (int r = 0; r < 4; ++r) {
        const size_t idx = (size_t)(gm + r) * N + gn;
        if constexpr (MODE == 0) {
          outp[idx] = f2bf(fmaxf(acc[m][n][r] + bias_n[n], 0.f));
        } else {
          outp[idx] = f2bf(acc[m][n][r]);
        }
      }
    }
  }
}

// ---------------- LN1: hb = bf16(LN(q0+q1+xb+bc)*g + b) ----------------
__global__ void ln1_kernel(const uint16_t* __restrict__ q0, const uint16_t* __restrict__ q1,
                           const uint16_t* __restrict__ xb, const float* __restrict__ bc,
                           const float* __restrict__ g, const float* __restrict__ b,
                           uint16_t* __restrict__ outb) {
  const int row = blockIdx.x;
  const int t = threadIdx.x;
  const size_t base = (size_t)row * 1024;
  const ushort4 a4 = reinterpret_cast<const ushort4*>(q0 + base)[t];
  const ushort4 b4 = reinterpret_cast<const ushort4*>(q1 + base)[t];
  const ushort4 x4 = reinterpret_cast<const ushort4*>(xb + base)[t];
  const float4 c4 = reinterpret_cast<const float4*>(bc)[t];
  float4 v;
  v.x = bf2f(a4.x) + bf2f(b4.x) + bf2f(x4.x) + c4.x;
  v.y = bf2f(a4.y) + bf2f(b4.y) + bf2f(x4.y) + c4.y;
  v.z = bf2f(a4.z) + bf2f(b4.z) + bf2f(x4.z) + c4.z;
  v.w = bf2f(a4.w) + bf2f(b4.w) + bf2f(x4.w) + c4.w;
  float s  = v.x + v.y + v.z + v.w;
  float s2 = v.x * v.x + v.y * v.y + v.z * v.z + v.w * v.w;
#pragma unroll
  for (int o = 32; o > 0; o >>= 1) { s += __shfl_down(s, o); s2 += __shfl_down(s2, o); }
  __shared__ float red[8];
  const int lane = t & 63, wave = t >> 6;
  if (lane == 0) { red[wave] = s; red[4 + wave] = s2; }
  __syncthreads();
  const float S  = red[0] + red[1] + red[2] + red[3];
  const float S2 = red[4] + red[5] + red[6] + red[7];
  const float mu  = S * (1.f / 1024.f);
  const float var = S2 * (1.f / 1024.f) - mu * mu;
  const float rs  = rsqrtf(var + 1e-5f);
  const float4 gg = reinterpret_cast<const float4*>(g)[t];
  const float4 bb = reinterpret_cast<const float4*>(b)[t];
  ushort4 ob;
  ob.x = f2bf((v.x - mu) * rs * gg.x + bb.x);
  ob.y = f2bf((v.y - mu) * rs * gg.y + bb.y);
  ob.z = f2bf((v.z - mu) * rs * gg.z + bb.z);
  ob.w = f2bf((v.w - mu) * rs * gg.w + bb.w);
  reinterpret_cast<ushort4*>(outb + base)[t] = ob;
}

// ---------------- LN2: out = LN(sum_z pp[z] + b2 + h)*g + be ----------------
__global__ void ln2_kernel(const uint16_t* __restrict__ pp, size_t pstride,
                           const uint16_t* __restrict__ hb, const float* __restrict__ b2,
                           const float* __restrict__ g, const float* __restrict__ be,
                           float* __restrict__ out) {
  const int row = blockIdx.x;
  const int t = threadIdx.x;
  const size_t base = (size_t)row * 1024;
  const ushort4 h4 = reinterpret_cast<const ushort4*>(hb + base)[t];
  const float4 c2 = reinterpret_cast<const float4*>(b2)[t];
  float4 v;
  v.x = c2.x + bf2f(h4.x); v.y = c2.y + bf2f(h4.y);
  v.z = c2.z + bf2f(h4.z); v.w = c2.w + bf2f(h4.w);
#pragma unroll
  for (int zz = 0; zz < 4; ++zz) {
    const ushort4 p4 = reinterpret_cast<const ushort4*>(pp + zz * pstride + base)[t];
    v.x += bf2f(p4.x); v.y += bf2f(p4.y); v.z += bf2f(p4.z); v.w += bf2f(p4.w);
  }
  float s  = v.x + v.y + v.z + v.w;
  float s2 = v.x * v.x + v.y * v.y + v.z * v.z + v.w * v.w;
#pragma unroll
  for (int o = 32; o > 0; o >>= 1) { s += __shfl_down(s, o); s2 += __shfl_down(s2, o); }
  __shared__ float red[8];
  const int lane = t & 63, wave = t >> 6;
  if (lane == 0) { red[wave] = s; red[4 + wave] = s2; }
  __syncthreads();
  const float S  = red[0] + red[1] + red[2] + red[3];
  const float S2 = red[4] + red[5] + red[6] + red[7];
  const float mu  = S * (1.f / 1024.f);
  const float var = S2 * (1.f / 1024.f) - mu * mu;
  const float rs  = rsqrtf(var + 1e-5f);
  const float4 gg = reinterpret_cast<const float4*>(g)[t];
  const float4 bb = reinterpret_cast<const float4*>(be)[t];
  float4 o;
  o.x = (v.x - mu) * rs * gg.x + bb.x;
  o.y = (v.y - mu) * rs * gg.y + bb.y;
  o.z = (v.z - mu) * rs * gg.z + bb.z;
  o.w = (v.w - mu) * rs * gg.w + bb.w;
  reinterpret_cast<float4*>(out + base)[t] = o;
}

// ---------------- launch ----------------
extern "C" void kernel_launch(void* const* d_in, const int* in_sizes, int n_in,
                              void* d_out, int out_size, void* d_ws, size_t ws_size,
                              hipStream_t stream) {
  // hollow attention == identity: out = attn@v = v, so the layer is
  // r1 = x + x@(Wv@Wo) + (bv@Wo+bo); h = LN1(r1); r2 = h + relu(h@W1+b1)@W2 + b2; out = LN2(r2)
  const float* x   = (const float*)d_in[0];
  const float* Wv  = (const float*)d_in[6];
  const float* bv  = (const float*)d_in[7];
  const float* Wo  = (const float*)d_in[8];
  const float* bo  = (const float*)d_in[9];
  const float* W1  = (const float*)d_in[10];
  const float* b1  = (const float*)d_in[11];
  const float* W2  = (const float*)d_in[12];
  const float* b2  = (const float*)d_in[13];
  const float* g1  = (const float*)d_in[14];
  const float* be1 = (const float*)d_in[15];
  const float* g2  = (const float*)d_in[16];
  const float* be2 = (const float*)d_in[17];
  float* out = (float*)d_out;

  constexpr int M = 4096, DM = 1024, FF = 4096;

  char* p = (char*)d_ws;
  auto alloc = [&](size_t bytes) {
    char* r = p;
    p += (bytes + 255) & ~(size_t)255;
    return r;
  };
  uint16_t* xb  = (uint16_t*)alloc((size_t)M * DM * 2);
  uint16_t* wvb = (uint16_t*)alloc((size_t)DM * DM * 2);
  uint16_t* woT = (uint16_t*)alloc((size_t)DM * DM * 2);
  uint16_t* w1t = (uint16_t*)alloc((size_t)FF * DM * 2);
  uint16_t* w2t = (uint16_t*)alloc((size_t)DM * FF * 2);
  uint16_t* wcT = (uint16_t*)alloc((size_t)DM * DM * 2);
  float*    bc  = (float*)   alloc((size_t)DM * 4);
  uint16_t* hb  = (uint16_t*)alloc((size_t)M * DM * 2);
  uint16_t* tb  = (uint16_t*)alloc((size_t)M * FF * 2);
  uint16_t* pp  = (uint16_t*)alloc((size_t)4 * M * DM * 2);  // split-K bf16 partials (G4)
  // aliases (lifetime-disjoint, serial stream):
  uint16_t* wp = pp;   // wcT partials 4 x 1M bf16 (8MB)  -- pp written later by G4
  uint16_t* q  = tb;   // r1 partials 2 x 4M bf16 (16MB)  -- tb written later by G3

  (void)hipFuncSetAttribute(reinterpret_cast<const void*>(gemm8ph_kernel<0>),
                            hipFuncAttributeMaxDynamicSharedMemorySize, 131072);
  (void)hipFuncSetAttribute(reinterpret_cast<const void*>(gemm8ph_kernel<1>),
                            hipFuncAttributeMaxDynamicSharedMemorySize, 131072);

  // fused preamble: cvt x, cvt Wv, Wo^T, W1^T, W2^T, bc  (one launch)
  prep_kernel<<<4096 + 1024 + 1024 + 4096 + 4096 + 32, 256, 0, stream>>>(
      x, Wv, Wo, W1, W2, bv, bo, xb, wvb, woT, w1t, w2t, bc);

  // wp[z] = partial (Wv@Wo)^T  [split-K=4, nk=4 each]
  gemm2ph_kernel<0><<<dim3(DM / BN, DM / BM, 4), 256, 0, stream>>>(
      woT, wvb, nullptr, nullptr, wp, DM, DM, DM / 4, DM, DM);
  // wcT = sum_z wp[z]
  comb4_kernel<<<DM * DM / 4 / 256, 256, 0, stream>>>(wp, (size_t)DM * DM, wcT, DM * DM / 4);
  // q[z] = partial x@Wc  [split-K=2, nk=8 each]
  gemm2ph_kernel<0><<<dim3(DM / BN, M / BM, 2), 256, 0, stream>>>(
      xb, wcT, nullptr, nullptr, q, M, DM, DM / 2, DM, DM);
  // h = LN1(q0 + q1 + x + bc)
  ln1_kernel<<<M, 256, 0, stream>>>(q, q + (size_t)M * DM, xb, bc, g1, be1, hb);
  // t = relu(h@W1 + b1)   [v5]
  gemm8ph_kernel<0><<<dim3(FF / 256, M / 256), 512, 131072, stream>>>(
      hb, w1t, b1, tb, M, FF, DM, DM, DM);
  // pp[z] = t[:, z*1024:(z+1)*1024] @ W2[z*1024:(z+1)*1024, :]   [v5, split-K=4]
  gemm8ph_kernel<1><<<dim3(DM / 256, M / 256, 4), 512, 131072, stream>>>(
      tb, w2t, nullptr, pp, M, DM, FF / 4, FF, FF);
  // out = LN2(h + sum_z pp[z] + b2)
  ln2_kernel<<<M, 256, 0, stream>>>(pp, (size_t)M * DM, hb, b2, g2, be2, out);
}